// Round 12
// baseline (523.933 us; speedup 1.0000x reference)
//
#include <hip/hip_runtime.h>
#include <hip/hip_fp16.h>

// NodeGCN: 3x GCNConv(H=20) + BN/ReLU + final linear, N=100K, E=3.2M.
// R18 = R17 (492.7us best: 4B adaptive edge payload) + non-agg fixes:
//  - R17 post-mortem: agg FLAT with halved se stream -> agg is at its
//    structural floor (~88us; 7 falsified models). Attack the other 230us.
//  - hist/scatter GB 512 -> 1024: they ran at 19% occupancy (2 blocks/CU);
//    both are latency/parallelism-bound (R12/R16 ladder: 128->127us,
//    256->97, 512->88). 4 blocks/CU halves the stall exposure. With 4B
//    payloads, 4-edge runs still only ~51MB WRITE (~8us BW).
//  - gemm: 4 outputs/thread -> 5 ds_read_b128 per 16 FMA (was 8), stores
//    5x8B per row (was 20x2B). gemm1 was LDS-read-bound.
//  - agg byte-identical to R17.

#define HD 20
#define EPS 1e-5f
#define BSH 7            // 128 nodes per bucket
#define NBMAX 1024
#define CAP 5632         // finalize: max 8B edges per bucket staged in LDS
#define CAPE 2816        // agg: max 8B edges per block staged in LDS

typedef float __attribute__((ext_vector_type(4))) f4v;

__device__ __forceinline__ float4 ntld4(const float* p) {
    f4v v = __builtin_nontemporal_load((const f4v*)p);
    return make_float4(v.x, v.y, v.z, v.w);
}

__global__ __launch_bounds__(1024)
void init_kernel(int* bcnt, float* stats, float* zero20, int* eflag, int nbv) {
    int t = threadIdx.x;
    if (t < nbv) bcnt[t] = 0;
    if (t < 80) stats[t] = 0.0f;
    if (t < HD) zero20[t] = 0.0f;
    if (t == 0) eflag[0] = 1;
}

// hist + all-ones edge-weight check
__global__ __launch_bounds__(256)
void bucket_hist_kernel(const int* __restrict__ dst, const float* __restrict__ ew,
                        int* __restrict__ bcnt, int* __restrict__ eflag,
                        int E, int chunk, int nbv) {
    __shared__ int lh[NBMAX];
    __shared__ int okf;
    if (threadIdx.x == 0) okf = 1;
    for (int i = threadIdx.x; i < nbv; i += 256) lh[i] = 0;
    __syncthreads();
    int s = blockIdx.x * chunk;
    int e = s + chunk; if (e > E) e = E;
    for (int j = s + threadIdx.x; j < e; j += 256) {
        atomicAdd(&lh[dst[j] >> BSH], 1);
        if (ew[j] != 1.0f) okf = 0;         // only 0 ever written: race-safe
    }
    __syncthreads();
    for (int i = threadIdx.x; i < nbv; i += 256)
        if (lh[i]) atomicAdd(&bcnt[i], lh[i]);
    if (threadIdx.x == 0 && !okf) eflag[0] = 0;
}

// single block: exclusive scan bcnt[0..nbv) -> bstart, init bcur, row_start[N]=E
__global__ __launch_bounds__(1024)
void bucket_scan_kernel(const int* __restrict__ bcnt, int* __restrict__ bstart,
                        int* __restrict__ bcur, int* __restrict__ row_start,
                        int n, int E, int nbv) {
    __shared__ int s[1024];
    int t = threadIdx.x;
    int v = (t < nbv) ? bcnt[t] : 0;
    s[t] = v;
    __syncthreads();
    for (int off = 1; off < 1024; off <<= 1) {
        int u = (t >= off) ? s[t - off] : 0;
        __syncthreads();
        s[t] += u;
        __syncthreads();
    }
    if (t < nbv) { int st = s[t] - v; bstart[t] = st; bcur[t] = st; }
    if (t == 0) { bstart[nbv] = E; row_start[n] = E; }
}

// scatter edges into bucket-grouped tmp; 4B (src|local<<20) fast path,
// 8B (src|local<<20, ew) fallback.
__global__ __launch_bounds__(256)
void scatter_kernel(const int* __restrict__ src, const int* __restrict__ dst,
                    const float* __restrict__ ew, const int* __restrict__ eflag,
                    int* __restrict__ bcur, int2* __restrict__ tmp,
                    int E, int chunk, int nbv) {
    __shared__ int lh[NBMAX];
    __shared__ int lbase[NBMAX];
    for (int i = threadIdx.x; i < nbv; i += 256) lh[i] = 0;
    __syncthreads();
    int s = blockIdx.x * chunk;
    int e = s + chunk; if (e > E) e = E;
    for (int j = s + threadIdx.x; j < e; j += 256)
        atomicAdd(&lh[dst[j] >> BSH], 1);
    __syncthreads();
    for (int i = threadIdx.x; i < nbv; i += 256) {
        int c = lh[i];
        lbase[i] = c ? atomicAdd(&bcur[i], c) : 0;
        lh[i] = 0;                         // reuse as local cursor
    }
    __syncthreads();
    if (eflag[0]) {
        int* tmp4 = (int*)tmp;
        for (int j = s + threadIdx.x; j < e; j += 256) {
            int d = dst[j];
            int b = d >> BSH;
            int pos = atomicAdd(&lh[b], 1);
            tmp4[lbase[b] + pos] = src[j] | ((d & ((1 << BSH) - 1)) << 20);
        }
    } else {
        for (int j = s + threadIdx.x; j < e; j += 256) {
            int d = dst[j];
            int b = d >> BSH;
            int pos = atomicAdd(&lh[b], 1);
            tmp[lbase[b] + pos] = make_int2(src[j] | ((d & ((1 << BSH) - 1)) << 20),
                                           __float_as_int(ew[j]));
        }
    }
}

// one block per bucket: in-LDS counting sort by local dst; emit CSR + row_start + dinv
__global__ __launch_bounds__(256)
void finalize_kernel(const int2* __restrict__ tmp, const int* __restrict__ bstart,
                     const int* __restrict__ eflag,
                     int2* __restrict__ se, int* __restrict__ row_start,
                     float* __restrict__ dinv, int n) {
    __shared__ int hist[128];
    __shared__ float degs[128];
    __shared__ int off[128];
    __shared__ int cur[128];
    __shared__ int2 stage[CAP];
    int* stage4 = (int*)stage;              // 2*CAP ints in same LDS
    const int* tmp4 = (const int*)tmp;
    int* se4 = (int*)se;
    bool f4 = eflag[0] != 0;
    int b = blockIdx.x;
    int s0 = bstart[b], s1 = bstart[b + 1];
    int cnt = s1 - s0;
    int t = threadIdx.x;
    if (t < 128) { hist[t] = 0; degs[t] = 0.0f; cur[t] = 0; }
    __syncthreads();
    if (f4) {
        for (int j = s0 + t; j < s1; j += 256)
            atomicAdd(&hist[tmp4[j] >> 20], 1);
    } else {
        for (int j = s0 + t; j < s1; j += 256) {
            int2 r = tmp[j];
            int l = r.x >> 20;
            atomicAdd(&hist[l], 1);
            atomicAdd(&degs[l], __int_as_float(r.y));
        }
    }
    __syncthreads();
    if (t < 128) off[t] = hist[t];
    __syncthreads();
    for (int o = 1; o < 128; o <<= 1) {           // inclusive scan
        int u = (t < 128 && t >= o) ? off[t - o] : 0;
        __syncthreads();
        if (t < 128) off[t] += u;
        __syncthreads();
    }
    if (t < 128) {
        int node = (b << BSH) + t;
        if (node < n) {
            row_start[node] = s0 + off[t] - hist[t];   // exclusive
            float dg = f4 ? (float)hist[t] : degs[t];
            dinv[node] = rsqrtf(1.0f + dg);
        }
    }
    __syncthreads();
    if (f4) {
        if (cnt <= 2 * CAP) {
            for (int j = s0 + t; j < s1; j += 256) {
                int r = tmp4[j];
                int l = r >> 20;
                int p = (off[l] - hist[l]) + atomicAdd(&cur[l], 1);
                stage4[p] = r & 0xFFFFF;
            }
            __syncthreads();
            for (int k = t; k < cnt; k += 256) se4[s0 + k] = stage4[k];
        } else {
            for (int j = s0 + t; j < s1; j += 256) {
                int r = tmp4[j];
                int l = r >> 20;
                int p = (off[l] - hist[l]) + atomicAdd(&cur[l], 1);
                se4[s0 + p] = r & 0xFFFFF;
            }
        }
    } else {
        if (cnt <= CAP) {
            for (int j = s0 + t; j < s1; j += 256) {
                int2 r = tmp[j];
                int l = r.x >> 20;
                int p = (off[l] - hist[l]) + atomicAdd(&cur[l], 1);
                stage[p] = make_int2(r.x & 0xFFFFF, r.y);
            }
            __syncthreads();
            for (int k = t; k < cnt; k += 256) se[s0 + k] = stage[k];
        } else {
            for (int j = s0 + t; j < s1; j += 256) {
                int2 r = tmp[j];
                int l = r.x >> 20;
                int p = (off[l] - hist[l]) + atomicAdd(&cur[l], 1);
                se[s0 + p] = make_int2(r.x & 0xFFFFF, r.y);
            }
        }
    }
}

// hs[n,20](fp16) = ((in[n,FIN] @ W[FIN,20]) + cvec) * dinv[n]
// 4 outputs per thread: 5 ds_read_b128 per 16 FMA; 8B stores.
template<int FIN, int NPB>
__global__ __launch_bounds__(256)
void gemm_kernel(const float* __restrict__ in, const float* __restrict__ W,
                 const float* __restrict__ cvec, const float* __restrict__ dinv,
                 __half* __restrict__ hs, int n) {
    __shared__ float sWt[HD][FIN + 4];
    __shared__ float sIn[NPB][FIN + 4];
    __shared__ float sC[HD];
    for (int i = threadIdx.x; i < FIN * HD; i += 256) {
        int k = i / HD, f = i % HD;           // W row-major [k][f]
        sWt[f][k] = W[i];
    }
    if (threadIdx.x < HD) sC[threadIdx.x] = cvec[threadIdx.x];
    int base = blockIdx.x * NPB;
    int nb = n - base; if (nb > NPB) nb = NPB;
    int lim = n * FIN;
    const int Q = FIN / 4;
    for (int i = threadIdx.x; i < NPB * Q; i += 256) {
        int row = i / Q, c = (i % Q) * 4;
        int g = (base + row) * FIN + c;
        *(float4*)&sIn[row][c] = (g < lim) ? ntld4(&in[g])
                                           : make_float4(0.f, 0.f, 0.f, 0.f);
    }
    __syncthreads();
    for (int idx = threadIdx.x; idx < NPB * 5; idx += 256) {
        int nl = idx / 5, fq = idx % 5;       // 4 outputs: f = 4*fq .. 4*fq+3
        float a0 = 0.f, a1 = 0.f, a2 = 0.f, a3 = 0.f;
        #pragma unroll 4
        for (int k = 0; k < FIN; k += 4) {
            float4 x4 = *(const float4*)&sIn[nl][k];
            float4 w0 = *(const float4*)&sWt[4 * fq + 0][k];
            float4 w1 = *(const float4*)&sWt[4 * fq + 1][k];
            float4 w2 = *(const float4*)&sWt[4 * fq + 2][k];
            float4 w3 = *(const float4*)&sWt[4 * fq + 3][k];
            a0 = fmaf(x4.x, w0.x, a0); a0 = fmaf(x4.y, w0.y, a0);
            a0 = fmaf(x4.z, w0.z, a0); a0 = fmaf(x4.w, w0.w, a0);
            a1 = fmaf(x4.x, w1.x, a1); a1 = fmaf(x4.y, w1.y, a1);
            a1 = fmaf(x4.z, w1.z, a1); a1 = fmaf(x4.w, w1.w, a1);
            a2 = fmaf(x4.x, w2.x, a2); a2 = fmaf(x4.y, w2.y, a2);
            a2 = fmaf(x4.z, w2.z, a2); a2 = fmaf(x4.w, w2.w, a2);
            a3 = fmaf(x4.x, w3.x, a3); a3 = fmaf(x4.y, w3.y, a3);
            a3 = fmaf(x4.z, w3.z, a3); a3 = fmaf(x4.w, w3.w, a3);
        }
        if (nl < nb) {
            int node = base + nl;
            float di = dinv[node];
            __half2 h01 = __floats2half2_rn((a0 + sC[4 * fq + 0]) * di,
                                            (a1 + sC[4 * fq + 1]) * di);
            __half2 h23 = __floats2half2_rn((a2 + sC[4 * fq + 2]) * di,
                                            (a3 + sC[4 * fq + 3]) * di);
            uint2 pk = make_uint2(*(unsigned*)&h01, *(unsigned*)&h23);
            *(uint2*)&hs[(size_t)node * HD + 4 * fq] = pk;   // 8B aligned
        }
    }
}

#define FMA4(A, V, W) \
    A.x = fmaf(V.x, W, A.x); A.y = fmaf(V.y, W, A.y); \
    A.z = fmaf(V.z, W, A.z); A.w = fmaf(V.w, W, A.w);

#define ADD4(A, V) \
    A.x += V.x; A.y += V.y; A.z += V.z; A.w += V.w;

__device__ __forceinline__ float4 h4f2(uint2 u) {
    float2 f0 = __half22float2(*reinterpret_cast<const __half2*>(&u.x));
    float2 f1 = __half22float2(*reinterpret_cast<const __half2*>(&u.y));
    return make_float4(f0.x, f0.y, f1.x, f1.y);
}

// 40B packed row gather: dwordx4 + dwordx4 + dwordx2 (dword align suffices).
#define ROWLD(Q0, Q1, Q2, SRC) { \
    const char* rp_ = (const char*)hsb + (size_t)(SRC) * 40; \
    Q0 = *(const uint4*)rp_; \
    Q1 = *(const uint4*)(rp_ + 16); \
    Q2 = *(const uint2*)(rp_ + 32); }

// 8B-payload edge loop: depth-2 pipeline with per-edge weight.
#define AGG_LOOP(EDGEAT)                                                     \
    {                                                                        \
        int2 e = EDGEAT(j);                                                  \
        float w = __int_as_float(e.y);                                       \
        uint4 c0, c1; uint2 c2; ROWLD(c0, c1, c2, e.x)                       \
        while (true) {                                                       \
            int jn = j + 4;                                                  \
            bool more = jn < s1;                                             \
            int jp = more ? jn : j;                                          \
            int2 en = EDGEAT(jp);                                            \
            uint4 n0, n1; uint2 n2; ROWLD(n0, n1, n2, en.x)                  \
            float wn = __int_as_float(en.y);                                 \
            float4 v0 = h4f2(make_uint2(c0.x, c0.y));                        \
            float4 v1 = h4f2(make_uint2(c0.z, c0.w));                        \
            float4 v2 = h4f2(make_uint2(c1.x, c1.y));                        \
            float4 v3 = h4f2(make_uint2(c1.z, c1.w));                        \
            float4 v4 = h4f2(c2);                                            \
            FMA4(a0, v0, w) FMA4(a1, v1, w) FMA4(a2, v2, w)                  \
            FMA4(a3, v3, w) FMA4(a4, v4, w)                                  \
            if (!more) break;                                                \
            j = jn; w = wn;                                                  \
            c0 = n0; c1 = n1; c2 = n2;                                       \
        }                                                                    \
    }

// 4B-payload edge loop: weight == 1, pure adds.
#define AGG_LOOP4(EDGEAT)                                                    \
    {                                                                        \
        int e = EDGEAT(j);                                                   \
        uint4 c0, c1; uint2 c2; ROWLD(c0, c1, c2, e)                         \
        while (true) {                                                       \
            int jn = j + 4;                                                  \
            bool more = jn < s1;                                             \
            int jp = more ? jn : j;                                          \
            int en = EDGEAT(jp);                                             \
            uint4 n0, n1; uint2 n2; ROWLD(n0, n1, n2, en)                    \
            float4 v0 = h4f2(make_uint2(c0.x, c0.y));                        \
            float4 v1 = h4f2(make_uint2(c0.z, c0.w));                        \
            float4 v2 = h4f2(make_uint2(c1.x, c1.y));                        \
            float4 v3 = h4f2(make_uint2(c1.z, c1.w));                        \
            float4 v4 = h4f2(c2);                                            \
            ADD4(a0, v0) ADD4(a1, v1) ADD4(a2, v2)                           \
            ADD4(a3, v3) ADD4(a4, v4)                                        \
            if (!more) break;                                                \
            j = jn;                                                          \
            c0 = n0; c1 = n1; c2 = n2;                                       \
        }                                                                    \
    }

#define EDGE_LDS(jj)  sse[(jj) - sb0]
#define EDGE_GBL(jj)  se[(jj)]
#define EDGE_LDS4(jj) sse4[(jj) - sb0]
#define EDGE_GBL4(jj) se4[(jj)]

// MODE 0: layers 1/2 — write o row + BN stats.
// MODE 1: layer 3 — fuse final linear: out[i,0..9] from o1,o2 rows + in-reg o3.
// One node per 4-lane group; block's 64 nodes = contiguous se span staged in LDS.
template<int MODE>
__global__ __launch_bounds__(256)
void agg_kernel(const __half* __restrict__ hsb, const float* __restrict__ dinv,
                const int* __restrict__ row_start, const int2* __restrict__ se,
                const int* __restrict__ eflag,
                const float* __restrict__ bias, float* __restrict__ out,
                float* __restrict__ stat_sum, float* __restrict__ stat_sq,
                const float* __restrict__ o1, const float* __restrict__ o2,
                const float* __restrict__ Wlp, const float* __restrict__ blp,
                int n) {
    __shared__ int2 sse[CAPE];
    int* sse4 = (int*)sse;                  // 2*CAPE ints in same LDS
    const int* se4 = (const int*)se;
    __shared__ float ls[HD], lq[HD];
    __shared__ float sW[600];
    __shared__ float sb[10];
    bool f4 = eflag[0] != 0;
    int base = blockIdx.x * 64;              // 256 threads / 4 lanes = 64 nodes
    int nEnd = base + 64; if (nEnd > n) nEnd = n;
    int sb0 = row_start[base];
    int sb1 = row_start[nEnd];
    int span = sb1 - sb0;
    bool ok = span <= (f4 ? 2 * CAPE : CAPE);
    if (MODE == 0) {
        if (threadIdx.x < HD) { ls[threadIdx.x] = 0.0f; lq[threadIdx.x] = 0.0f; }
    } else {
        for (int i = threadIdx.x; i < 600; i += 256) sW[i] = Wlp[i];
        if (threadIdx.x < 10) sb[threadIdx.x] = blp[threadIdx.x];
    }
    if (ok) {
        if (f4) {
            for (int k = threadIdx.x; k < span; k += 256)
                sse4[k] = __builtin_nontemporal_load(se4 + sb0 + k);
        } else {
            for (int k = threadIdx.x; k < span; k += 256) {
                long long v = __builtin_nontemporal_load(
                    (const long long*)(se + sb0 + k));
                sse[k] = *(const int2*)&v;
            }
        }
    }
    __syncthreads();
    int i = base + (threadIdx.x >> 2), lane = threadIdx.x & 3;
    if (i < n) {
        float di = dinv[i];
        int s0 = row_start[i], s1 = row_start[i + 1];
        float4 a0, a1, a2, a3, a4;
        if (lane == 0) {
            uint4 y0, y1; uint2 y2;
            ROWLD(y0, y1, y2, i)
            a0 = h4f2(make_uint2(y0.x, y0.y));
            a1 = h4f2(make_uint2(y0.z, y0.w));
            a2 = h4f2(make_uint2(y1.x, y1.y));
            a3 = h4f2(make_uint2(y1.z, y1.w));
            a4 = h4f2(y2);
        } else {
            a0 = a1 = a2 = a3 = a4 = make_float4(0.f, 0.f, 0.f, 0.f);
        }
        int j = s0 + lane;
        if (j < s1) {
            if (f4) {
                if (ok) { AGG_LOOP4(EDGE_LDS4) }
                else    { AGG_LOOP4(EDGE_GBL4) }
            } else {
                if (ok) { AGG_LOOP(EDGE_LDS) }
                else    { AGG_LOOP(EDGE_GBL) }
            }
        }
        #define REDX(A, M) \
            A.x += __shfl_xor(A.x, M); A.y += __shfl_xor(A.y, M); \
            A.z += __shfl_xor(A.z, M); A.w += __shfl_xor(A.w, M);
        #define RED4L(A) REDX(A, 1) REDX(A, 2)
        RED4L(a0) RED4L(a1) RED4L(a2) RED4L(a3) RED4L(a4)
        // all 4 lanes now hold the full sums
        float4 acc[5] = {a0, a1, a2, a3, a4};
        float va[HD];
        #pragma unroll
        for (int q = 0; q < 5; ++q) {
            float4 bb = *(const float4*)(bias + 4 * q);
            va[4 * q + 0] = fmaxf(fmaf(acc[q].x, di, bb.x), 0.0f);
            va[4 * q + 1] = fmaxf(fmaf(acc[q].y, di, bb.y), 0.0f);
            va[4 * q + 2] = fmaxf(fmaf(acc[q].z, di, bb.z), 0.0f);
            va[4 * q + 3] = fmaxf(fmaf(acc[q].w, di, bb.w), 0.0f);
        }
        if (MODE == 0) {
            if (lane == 0) {
                #pragma unroll
                for (int q = 0; q < 5; ++q) {
                    ((float4*)out)[i * 5 + q] = make_float4(
                        va[4 * q], va[4 * q + 1], va[4 * q + 2], va[4 * q + 3]);
                    int f = 4 * q;
                    atomicAdd(&ls[f + 0], va[f + 0]); atomicAdd(&lq[f + 0], va[f + 0] * va[f + 0]);
                    atomicAdd(&ls[f + 1], va[f + 1]); atomicAdd(&lq[f + 1], va[f + 1] * va[f + 1]);
                    atomicAdd(&ls[f + 2], va[f + 2]); atomicAdd(&lq[f + 2], va[f + 2] * va[f + 2]);
                    atomicAdd(&ls[f + 3], va[f + 3]); atomicAdd(&lq[f + 3], va[f + 3] * va[f + 3]);
                }
            }
        } else {
            // fused final: load o1,o2 rows (same addrs across quad -> L1 broadcast)
            float r1[HD], r2[HD];
            #pragma unroll
            for (int q = 0; q < 5; ++q) {
                *(float4*)&r1[4 * q] = ((const float4*)(o1 + (size_t)i * HD))[q];
                *(float4*)&r2[4 * q] = ((const float4*)(o2 + (size_t)i * HD))[q];
            }
            for (int c = lane; c < 10; c += 4) {
                float s = sb[c];
                #pragma unroll
                for (int k = 0; k < HD; ++k) s = fmaf(r1[k], sW[k * 10 + c], s);
                #pragma unroll
                for (int k = 0; k < HD; ++k) s = fmaf(r2[k], sW[(HD + k) * 10 + c], s);
                #pragma unroll
                for (int k = 0; k < HD; ++k) s = fmaf(va[k], sW[(2 * HD + k) * 10 + c], s);
                out[(size_t)i * 10 + c] = s;
            }
        }
    }
    if (MODE == 0) {
        __syncthreads();
        if (threadIdx.x < HD) {
            atomicAdd(&stat_sum[threadIdx.x], ls[threadIdx.x]);
            atomicAdd(&stat_sq[threadIdx.x], lq[threadIdx.x]);
        }
    }
}

// BN finalize + fold into next conv: scsh_out = (scale,shift);
// Wp[k][f] = sc[k]*W[k][f]; cvec[f] = sum_k sh[k]*W[k][f]
__global__ __launch_bounds__(512)
void bn_adjust_kernel(const float* __restrict__ sum, const float* __restrict__ sq,
                      const float* __restrict__ g, const float* __restrict__ be,
                      const float* __restrict__ W, float* __restrict__ scsh_out,
                      float* __restrict__ Wp, float* __restrict__ cvec, int n) {
    __shared__ float ssc[HD], ssh[HD];
    int t = threadIdx.x;
    if (t < HD) {
        float inv_n = 1.0f / (float)n;
        float m = sum[t] * inv_n;
        float var = sq[t] * inv_n - m * m;
        float sc = g[t] * rsqrtf(var + EPS);
        float sh = be[t] - m * sc;
        ssc[t] = sc; ssh[t] = sh;
        scsh_out[t] = sc; scsh_out[HD + t] = sh;
    }
    __syncthreads();
    if (t < HD * HD) Wp[t] = ssc[t / HD] * W[t];
    if (t < HD) {
        float acc = 0.0f;
        #pragma unroll
        for (int k = 0; k < HD; ++k) acc = fmaf(ssh[k], W[k * HD + t], acc);
        cvec[t] = acc;
    }
}

// second BN: same as above + build Wlp/blp for the fused final.
// Wlp rows: 0..19 *= sc1, 20..39 *= sc2, 40..59 UNSCALED (o3 block).
__global__ __launch_bounds__(640)
void bn_adjust2_kernel(const float* __restrict__ sum, const float* __restrict__ sq,
                       const float* __restrict__ g, const float* __restrict__ be,
                       const float* __restrict__ W, float* __restrict__ scsh_out,
                       float* __restrict__ Wp, float* __restrict__ cvec,
                       const float* __restrict__ Wl, const float* __restrict__ bl,
                       const float* __restrict__ scsh1,
                       float* __restrict__ Wlp, float* __restrict__ blp, int n) {
    __shared__ float ssc[HD], ssh[HD];
    int t = threadIdx.x;
    if (t < HD) {
        float inv_n = 1.0f / (float)n;
        float m = sum[t] * inv_n;
        float var = sq[t] * inv_n - m * m;
        float sc = g[t] * rsqrtf(var + EPS);
        float sh = be[t] - m * sc;
        ssc[t] = sc; ssh[t] = sh;
        scsh_out[t] = sc; scsh_out[HD + t] = sh;
    }
    __syncthreads();
    if (t < HD * HD) Wp[t] = ssc[t / HD] * W[t];
    if (t < HD) {
        float acc = 0.0f;
        #pragma unroll
        for (int k = 0; k < HD; ++k) acc = fmaf(ssh[k], W[k * HD + t], acc);
        cvec[t] = acc;
    }
    if (t < 600) {
        int k = t / 10;
        float s = (k < HD) ? scsh1[k] : (k < 2 * HD) ? ssc[k - HD] : 1.0f;
        Wlp[t] = s * Wl[t];
    }
    if (t < 10) {
        float acc = bl[t];
        #pragma unroll
        for (int k = 0; k < HD; ++k) acc = fmaf(scsh1[HD + k], Wl[k * 10 + t], acc);
        #pragma unroll
        for (int k = 0; k < HD; ++k) acc = fmaf(ssh[k], Wl[(HD + k) * 10 + t], acc);
        blp[t] = acc;
    }
}

extern "C" void kernel_launch(void* const* d_in, const int* in_sizes, int n_in,
                              void* d_out, int out_size, void* d_ws, size_t ws_size,
                              hipStream_t stream) {
    const float* x   = (const float*)d_in[0];
    const int*   ei  = (const int*)d_in[1];
    const float* ew  = (const float*)d_in[2];
    const float* W1  = (const float*)d_in[3];
    const float* b1  = (const float*)d_in[4];
    const float* g1  = (const float*)d_in[5];
    const float* be1 = (const float*)d_in[6];
    const float* W2  = (const float*)d_in[7];
    const float* b2  = (const float*)d_in[8];
    const float* g2  = (const float*)d_in[9];
    const float* be2 = (const float*)d_in[10];
    const float* W3  = (const float*)d_in[11];
    const float* b3  = (const float*)d_in[12];
    const float* Wl  = (const float*)d_in[13];
    const float* bl  = (const float*)d_in[14];
    float* out = (float*)d_out;

    const int F = in_sizes[3] / HD;       // 128
    const int N = in_sizes[0] / F;        // 100000
    const int E = in_sizes[2];            // 3200000
    const int* src = ei;
    const int* dst = ei + E;
    const int nbv = (N + 127) >> BSH;     // 782 buckets

    char* p = (char*)d_ws;
    auto alloc = [&](size_t bytes) -> void* {
        void* r = (void*)p;
        p += (bytes + 255) & ~(size_t)255;
        return r;
    };
    size_t nh4 = (size_t)N * HD * 4;                         // 8e6 B
    int2*  se      = (int2*) alloc((size_t)E * 8);           // CSR payload
    char*  regionA = (char*) alloc((size_t)E * 8);           // tmp -> hs|_|o1r
    float* o2r     = (float*)alloc(nh4);
    float* dinv    = (float*)alloc((size_t)N * 4);
    int*   row_start = (int*)alloc((size_t)(N + 1) * 4);
    int*   bcnt    = (int*)  alloc(NBMAX * 4);
    int*   bstart  = (int*)  alloc((NBMAX + 1) * 4);
    int*   bcur    = (int*)  alloc(NBMAX * 4);
    float* stats   = (float*)alloc(80 * 4);   // sum1,sq1,sum2,sq2
    float* scsh    = (float*)alloc(80 * 4);   // sc1,sh1,sc2,sh2
    float* zero20  = (float*)alloc(20 * 4);
    float* W2p     = (float*)alloc(400 * 4);
    float* c2      = (float*)alloc(20 * 4);
    float* W3p     = (float*)alloc(400 * 4);
    float* c3      = (float*)alloc(20 * 4);
    float* Wlp     = (float*)alloc(600 * 4);
    float* blp     = (float*)alloc(12 * 4);
    int*   eflag   = (int*)  alloc(4);

    int2*   tmp = (int2*)regionA;
    __half* hs  = (__half*)regionA;                 // 4 MB fp16, fits per-XCD L2
    float*  o1r = (float*)(regionA + 2 * nh4);

    const int B = 256;
    const int GB = 1024;                         // blocks for hist/scatter (4/CU)
    const int chunk = (E + GB - 1) / GB;         // 3125
    int gAgg = (4 * N + B - 1) / B;              // 1563 (4 lanes/node, 64 nodes/block)

    // ---- graph build (shared by all 3 layers) ----
    hipLaunchKernelGGL(init_kernel, dim3(1), dim3(1024), 0, stream,
                       bcnt, stats, zero20, eflag, nbv);
    hipLaunchKernelGGL(bucket_hist_kernel, dim3(GB), dim3(B), 0, stream,
                       dst, ew, bcnt, eflag, E, chunk, nbv);
    hipLaunchKernelGGL(bucket_scan_kernel, dim3(1), dim3(1024), 0, stream,
                       bcnt, bstart, bcur, row_start, N, E, nbv);
    hipLaunchKernelGGL(scatter_kernel, dim3(GB), dim3(B), 0, stream,
                       src, dst, ew, eflag, bcur, tmp, E, chunk, nbv);
    hipLaunchKernelGGL(finalize_kernel, dim3(nbv), dim3(B), 0, stream,
                       tmp, bstart, eflag, se, row_start, dinv, N);

    // ---- layer 1 (no upstream BN: cvec = 0, bias = b1) ----
    hipLaunchKernelGGL((gemm_kernel<128, 16>), dim3((N + 15) / 16), dim3(B), 0, stream,
                       x, W1, zero20, dinv, hs, N);
    hipLaunchKernelGGL((agg_kernel<0>), dim3(gAgg), dim3(B), 0, stream,
                       hs, dinv, row_start, se, eflag, b1, o1r,
                       stats, stats + 20, nullptr, nullptr, nullptr, nullptr, N);
    hipLaunchKernelGGL(bn_adjust_kernel, dim3(1), dim3(512), 0, stream,
                       stats, stats + 20, g1, be1, W2, scsh, W2p, c2, N);

    // ---- layer 2 (BN1 scale in W2p, shift in c2 pre-agg; bias = raw b2) ----
    hipLaunchKernelGGL((gemm_kernel<HD, 64>), dim3((N + 63) / 64), dim3(B), 0, stream,
                       o1r, W2p, c2, dinv, hs, N);
    hipLaunchKernelGGL((agg_kernel<0>), dim3(gAgg), dim3(B), 0, stream,
                       hs, dinv, row_start, se, eflag, b2, o2r,
                       stats + 40, stats + 60, nullptr, nullptr, nullptr, nullptr, N);
    hipLaunchKernelGGL(bn_adjust2_kernel, dim3(1), dim3(640), 0, stream,
                       stats + 40, stats + 60, g2, be2, W3, scsh + 40, W3p, c3,
                       Wl, bl, scsh, Wlp, blp, N);

    // ---- layer 3 + fused final linear (writes d_out directly) ----
    hipLaunchKernelGGL((gemm_kernel<HD, 64>), dim3((N + 63) / 64), dim3(B), 0, stream,
                       o2r, W3p, c3, dinv, hs, N);
    hipLaunchKernelGGL((agg_kernel<1>), dim3(gAgg), dim3(B), 0, stream,
                       hs, dinv, row_start, se, eflag, b3, out,
                       nullptr, nullptr, o1r, o2r, Wlp, blp, N);
}

// Round 13
// 489.284 us; speedup vs baseline: 1.0708x; 1.0708x over previous
//
#include <hip/hip_runtime.h>
#include <hip/hip_fp16.h>

// NodeGCN: 3x GCNConv(H=20) + BN/ReLU + final linear, N=100K, E=3.2M.
// R19 = R17 (492.7us best) + staged scatter; gemm-4-output kept; GB=512.
//  - R18 post-mortem: GB=1024 scatter regressed (94us, WRITE 99MB): 4-edge
//    runs -> partial-line explosion. Ladder {128,256,512,1024} -> {127,97,
//    88,94}us: two-sided tradeoff, GB=512 is the saddle. Structural fix:
//  - STAGED SCATTER: block sorts its 6250-edge chunk by bucket in LDS
//    (hist -> 782-entry scan -> stage[]+sbid[]), then copies out in bucket
//    order: waves write consecutive staged slots = consecutive addresses
//    within runs -> ~8-16 lines/wave-store vs 64. Fallback = R17 path.
//  - agg/finalize/gemm byte-identical to R18 (gemm 4-output was neutral-
//    to-positive; R18's regression was all scatter).

#define HD 20
#define EPS 1e-5f
#define BSH 7            // 128 nodes per bucket
#define NBMAX 1024
#define CAP 5632         // finalize: max 8B edges per bucket staged in LDS
#define CAPE 2816        // agg: max 8B edges per block staged in LDS
#define CHUNKMAX 6400    // staged scatter: max edges per block chunk

typedef float __attribute__((ext_vector_type(4))) f4v;

__device__ __forceinline__ float4 ntld4(const float* p) {
    f4v v = __builtin_nontemporal_load((const f4v*)p);
    return make_float4(v.x, v.y, v.z, v.w);
}

__global__ __launch_bounds__(1024)
void init_kernel(int* bcnt, float* stats, float* zero20, int* eflag, int nbv) {
    int t = threadIdx.x;
    if (t < nbv) bcnt[t] = 0;
    if (t < 80) stats[t] = 0.0f;
    if (t < HD) zero20[t] = 0.0f;
    if (t == 0) eflag[0] = 1;
}

// hist + all-ones edge-weight check
__global__ __launch_bounds__(256)
void bucket_hist_kernel(const int* __restrict__ dst, const float* __restrict__ ew,
                        int* __restrict__ bcnt, int* __restrict__ eflag,
                        int E, int chunk, int nbv) {
    __shared__ int lh[NBMAX];
    __shared__ int okf;
    if (threadIdx.x == 0) okf = 1;
    for (int i = threadIdx.x; i < nbv; i += 256) lh[i] = 0;
    __syncthreads();
    int s = blockIdx.x * chunk;
    int e = s + chunk; if (e > E) e = E;
    for (int j = s + threadIdx.x; j < e; j += 256) {
        atomicAdd(&lh[dst[j] >> BSH], 1);
        if (ew[j] != 1.0f) okf = 0;         // only 0 ever written: race-safe
    }
    __syncthreads();
    for (int i = threadIdx.x; i < nbv; i += 256)
        if (lh[i]) atomicAdd(&bcnt[i], lh[i]);
    if (threadIdx.x == 0 && !okf) eflag[0] = 0;
}

// single block: exclusive scan bcnt[0..nbv) -> bstart, init bcur, row_start[N]=E
__global__ __launch_bounds__(1024)
void bucket_scan_kernel(const int* __restrict__ bcnt, int* __restrict__ bstart,
                        int* __restrict__ bcur, int* __restrict__ row_start,
                        int n, int E, int nbv) {
    __shared__ int s[1024];
    int t = threadIdx.x;
    int v = (t < nbv) ? bcnt[t] : 0;
    s[t] = v;
    __syncthreads();
    for (int off = 1; off < 1024; off <<= 1) {
        int u = (t >= off) ? s[t - off] : 0;
        __syncthreads();
        s[t] += u;
        __syncthreads();
    }
    if (t < nbv) { int st = s[t] - v; bstart[t] = st; bcur[t] = st; }
    if (t == 0) { bstart[nbv] = E; row_start[n] = E; }
}

// scatter edges into bucket-grouped tmp.
// Fast path (4B payload, chunk fits LDS): block-local counting sort by bucket
// into stage[], then bucket-ordered coalesced copy-out.
// Fallback: R17's direct scattered-write path (8B, or oversized chunk).
__global__ __launch_bounds__(256)
void scatter_kernel(const int* __restrict__ src, const int* __restrict__ dst,
                    const float* __restrict__ ew, const int* __restrict__ eflag,
                    int* __restrict__ bcur, int2* __restrict__ tmp,
                    int E, int chunk, int nbv) {
    __shared__ int lh[NBMAX];
    __shared__ int lofs[NBMAX];
    __shared__ int lbase[NBMAX];
    __shared__ int sc[256];
    __shared__ int stage[CHUNKMAX];
    __shared__ unsigned short sbid[CHUNKMAX];
    int t = threadIdx.x;
    int s = blockIdx.x * chunk;
    int e = s + chunk; if (e > E) e = E;
    int cnt = e - s;
    bool f4 = eflag[0] != 0;
    for (int i = t; i < nbv; i += 256) lh[i] = 0;
    __syncthreads();
    for (int j = s + t; j < e; j += 256)
        atomicAdd(&lh[dst[j] >> BSH], 1);
    __syncthreads();
    if (f4 && cnt <= CHUNKMAX) {
        // ---- staged path ----
        // scan lh[0..nbv) -> lofs (exclusive, block-local); reserve global bases
        int base4 = t * 4;                       // thread handles 4 contiguous buckets
        int v0 = 0, v1 = 0, v2 = 0, v3 = 0, tsum = 0;
        if (base4 + 0 < nbv) { v0 = lh[base4 + 0]; tsum += v0; }
        if (base4 + 1 < nbv) { v1 = lh[base4 + 1]; tsum += v1; }
        if (base4 + 2 < nbv) { v2 = lh[base4 + 2]; tsum += v2; }
        if (base4 + 3 < nbv) { v3 = lh[base4 + 3]; tsum += v3; }
        sc[t] = tsum;
        __syncthreads();
        for (int off = 1; off < 256; off <<= 1) {
            int u = (t >= off) ? sc[t - off] : 0;
            __syncthreads();
            sc[t] += u;
            __syncthreads();
        }
        int ex = sc[t] - tsum;
        if (base4 + 0 < nbv) { lofs[base4 + 0] = ex; ex += v0; }
        if (base4 + 1 < nbv) { lofs[base4 + 1] = ex; ex += v1; }
        if (base4 + 2 < nbv) { lofs[base4 + 2] = ex; ex += v2; }
        if (base4 + 3 < nbv) { lofs[base4 + 3] = ex; ex += v3; }
        for (int i = t; i < nbv; i += 256) {
            int c = lh[i];
            lbase[i] = c ? atomicAdd(&bcur[i], c) : 0;
            lh[i] = 0;                           // reuse as local cursor
        }
        __syncthreads();
        for (int j = s + t; j < e; j += 256) {
            int d = dst[j];
            int b = d >> BSH;
            int p = lofs[b] + atomicAdd(&lh[b], 1);
            stage[p] = src[j] | ((d & ((1 << BSH) - 1)) << 20);
            sbid[p] = (unsigned short)b;
        }
        __syncthreads();
        int* tmp4 = (int*)tmp;
        for (int k = t; k < cnt; k += 256) {
            int b = sbid[k];
            tmp4[lbase[b] + (k - lofs[b])] = stage[k];
        }
    } else {
        // ---- fallback: direct scattered writes (R17 path) ----
        for (int i = t; i < nbv; i += 256) {
            int c = lh[i];
            lbase[i] = c ? atomicAdd(&bcur[i], c) : 0;
            lh[i] = 0;                           // reuse as local cursor
        }
        __syncthreads();
        if (f4) {
            int* tmp4 = (int*)tmp;
            for (int j = s + t; j < e; j += 256) {
                int d = dst[j];
                int b = d >> BSH;
                int pos = atomicAdd(&lh[b], 1);
                tmp4[lbase[b] + pos] = src[j] | ((d & ((1 << BSH) - 1)) << 20);
            }
        } else {
            for (int j = s + t; j < e; j += 256) {
                int d = dst[j];
                int b = d >> BSH;
                int pos = atomicAdd(&lh[b], 1);
                tmp[lbase[b] + pos] = make_int2(src[j] | ((d & ((1 << BSH) - 1)) << 20),
                                               __float_as_int(ew[j]));
            }
        }
    }
}

// one block per bucket: in-LDS counting sort by local dst; emit CSR + row_start + dinv
__global__ __launch_bounds__(256)
void finalize_kernel(const int2* __restrict__ tmp, const int* __restrict__ bstart,
                     const int* __restrict__ eflag,
                     int2* __restrict__ se, int* __restrict__ row_start,
                     float* __restrict__ dinv, int n) {
    __shared__ int hist[128];
    __shared__ float degs[128];
    __shared__ int off[128];
    __shared__ int cur[128];
    __shared__ int2 stage[CAP];
    int* stage4 = (int*)stage;              // 2*CAP ints in same LDS
    const int* tmp4 = (const int*)tmp;
    int* se4 = (int*)se;
    bool f4 = eflag[0] != 0;
    int b = blockIdx.x;
    int s0 = bstart[b], s1 = bstart[b + 1];
    int cnt = s1 - s0;
    int t = threadIdx.x;
    if (t < 128) { hist[t] = 0; degs[t] = 0.0f; cur[t] = 0; }
    __syncthreads();
    if (f4) {
        for (int j = s0 + t; j < s1; j += 256)
            atomicAdd(&hist[tmp4[j] >> 20], 1);
    } else {
        for (int j = s0 + t; j < s1; j += 256) {
            int2 r = tmp[j];
            int l = r.x >> 20;
            atomicAdd(&hist[l], 1);
            atomicAdd(&degs[l], __int_as_float(r.y));
        }
    }
    __syncthreads();
    if (t < 128) off[t] = hist[t];
    __syncthreads();
    for (int o = 1; o < 128; o <<= 1) {           // inclusive scan
        int u = (t < 128 && t >= o) ? off[t - o] : 0;
        __syncthreads();
        if (t < 128) off[t] += u;
        __syncthreads();
    }
    if (t < 128) {
        int node = (b << BSH) + t;
        if (node < n) {
            row_start[node] = s0 + off[t] - hist[t];   // exclusive
            float dg = f4 ? (float)hist[t] : degs[t];
            dinv[node] = rsqrtf(1.0f + dg);
        }
    }
    __syncthreads();
    if (f4) {
        if (cnt <= 2 * CAP) {
            for (int j = s0 + t; j < s1; j += 256) {
                int r = tmp4[j];
                int l = r >> 20;
                int p = (off[l] - hist[l]) + atomicAdd(&cur[l], 1);
                stage4[p] = r & 0xFFFFF;
            }
            __syncthreads();
            for (int k = t; k < cnt; k += 256) se4[s0 + k] = stage4[k];
        } else {
            for (int j = s0 + t; j < s1; j += 256) {
                int r = tmp4[j];
                int l = r >> 20;
                int p = (off[l] - hist[l]) + atomicAdd(&cur[l], 1);
                se4[s0 + p] = r & 0xFFFFF;
            }
        }
    } else {
        if (cnt <= CAP) {
            for (int j = s0 + t; j < s1; j += 256) {
                int2 r = tmp[j];
                int l = r.x >> 20;
                int p = (off[l] - hist[l]) + atomicAdd(&cur[l], 1);
                stage[p] = make_int2(r.x & 0xFFFFF, r.y);
            }
            __syncthreads();
            for (int k = t; k < cnt; k += 256) se[s0 + k] = stage[k];
        } else {
            for (int j = s0 + t; j < s1; j += 256) {
                int2 r = tmp[j];
                int l = r.x >> 20;
                int p = (off[l] - hist[l]) + atomicAdd(&cur[l], 1);
                se[s0 + p] = make_int2(r.x & 0xFFFFF, r.y);
            }
        }
    }
}

// hs[n,20](fp16) = ((in[n,FIN] @ W[FIN,20]) + cvec) * dinv[n]
// 4 outputs per thread: 5 ds_read_b128 per 16 FMA; 8B stores.
template<int FIN, int NPB>
__global__ __launch_bounds__(256)
void gemm_kernel(const float* __restrict__ in, const float* __restrict__ W,
                 const float* __restrict__ cvec, const float* __restrict__ dinv,
                 __half* __restrict__ hs, int n) {
    __shared__ float sWt[HD][FIN + 4];
    __shared__ float sIn[NPB][FIN + 4];
    __shared__ float sC[HD];
    for (int i = threadIdx.x; i < FIN * HD; i += 256) {
        int k = i / HD, f = i % HD;           // W row-major [k][f]
        sWt[f][k] = W[i];
    }
    if (threadIdx.x < HD) sC[threadIdx.x] = cvec[threadIdx.x];
    int base = blockIdx.x * NPB;
    int nb = n - base; if (nb > NPB) nb = NPB;
    int lim = n * FIN;
    const int Q = FIN / 4;
    for (int i = threadIdx.x; i < NPB * Q; i += 256) {
        int row = i / Q, c = (i % Q) * 4;
        int g = (base + row) * FIN + c;
        *(float4*)&sIn[row][c] = (g < lim) ? ntld4(&in[g])
                                           : make_float4(0.f, 0.f, 0.f, 0.f);
    }
    __syncthreads();
    for (int idx = threadIdx.x; idx < NPB * 5; idx += 256) {
        int nl = idx / 5, fq = idx % 5;       // 4 outputs: f = 4*fq .. 4*fq+3
        float a0 = 0.f, a1 = 0.f, a2 = 0.f, a3 = 0.f;
        #pragma unroll 4
        for (int k = 0; k < FIN; k += 4) {
            float4 x4 = *(const float4*)&sIn[nl][k];
            float4 w0 = *(const float4*)&sWt[4 * fq + 0][k];
            float4 w1 = *(const float4*)&sWt[4 * fq + 1][k];
            float4 w2 = *(const float4*)&sWt[4 * fq + 2][k];
            float4 w3 = *(const float4*)&sWt[4 * fq + 3][k];
            a0 = fmaf(x4.x, w0.x, a0); a0 = fmaf(x4.y, w0.y, a0);
            a0 = fmaf(x4.z, w0.z, a0); a0 = fmaf(x4.w, w0.w, a0);
            a1 = fmaf(x4.x, w1.x, a1); a1 = fmaf(x4.y, w1.y, a1);
            a1 = fmaf(x4.z, w1.z, a1); a1 = fmaf(x4.w, w1.w, a1);
            a2 = fmaf(x4.x, w2.x, a2); a2 = fmaf(x4.y, w2.y, a2);
            a2 = fmaf(x4.z, w2.z, a2); a2 = fmaf(x4.w, w2.w, a2);
            a3 = fmaf(x4.x, w3.x, a3); a3 = fmaf(x4.y, w3.y, a3);
            a3 = fmaf(x4.z, w3.z, a3); a3 = fmaf(x4.w, w3.w, a3);
        }
        if (nl < nb) {
            int node = base + nl;
            float di = dinv[node];
            __half2 h01 = __floats2half2_rn((a0 + sC[4 * fq + 0]) * di,
                                            (a1 + sC[4 * fq + 1]) * di);
            __half2 h23 = __floats2half2_rn((a2 + sC[4 * fq + 2]) * di,
                                            (a3 + sC[4 * fq + 3]) * di);
            uint2 pk = make_uint2(*(unsigned*)&h01, *(unsigned*)&h23);
            *(uint2*)&hs[(size_t)node * HD + 4 * fq] = pk;   // 8B aligned
        }
    }
}

#define FMA4(A, V, W) \
    A.x = fmaf(V.x, W, A.x); A.y = fmaf(V.y, W, A.y); \
    A.z = fmaf(V.z, W, A.z); A.w = fmaf(V.w, W, A.w);

#define ADD4(A, V) \
    A.x += V.x; A.y += V.y; A.z += V.z; A.w += V.w;

__device__ __forceinline__ float4 h4f2(uint2 u) {
    float2 f0 = __half22float2(*reinterpret_cast<const __half2*>(&u.x));
    float2 f1 = __half22float2(*reinterpret_cast<const __half2*>(&u.y));
    return make_float4(f0.x, f0.y, f1.x, f1.y);
}

// 40B packed row gather: dwordx4 + dwordx4 + dwordx2 (dword align suffices).
#define ROWLD(Q0, Q1, Q2, SRC) { \
    const char* rp_ = (const char*)hsb + (size_t)(SRC) * 40; \
    Q0 = *(const uint4*)rp_; \
    Q1 = *(const uint4*)(rp_ + 16); \
    Q2 = *(const uint2*)(rp_ + 32); }

// 8B-payload edge loop: depth-2 pipeline with per-edge weight.
#define AGG_LOOP(EDGEAT)                                                     \
    {                                                                        \
        int2 e = EDGEAT(j);                                                  \
        float w = __int_as_float(e.y);                                       \
        uint4 c0, c1; uint2 c2; ROWLD(c0, c1, c2, e.x)                       \
        while (true) {                                                       \
            int jn = j + 4;                                                  \
            bool more = jn < s1;                                             \
            int jp = more ? jn : j;                                          \
            int2 en = EDGEAT(jp);                                            \
            uint4 n0, n1; uint2 n2; ROWLD(n0, n1, n2, en.x)                  \
            float wn = __int_as_float(en.y);                                 \
            float4 v0 = h4f2(make_uint2(c0.x, c0.y));                        \
            float4 v1 = h4f2(make_uint2(c0.z, c0.w));                        \
            float4 v2 = h4f2(make_uint2(c1.x, c1.y));                        \
            float4 v3 = h4f2(make_uint2(c1.z, c1.w));                        \
            float4 v4 = h4f2(c2);                                            \
            FMA4(a0, v0, w) FMA4(a1, v1, w) FMA4(a2, v2, w)                  \
            FMA4(a3, v3, w) FMA4(a4, v4, w)                                  \
            if (!more) break;                                                \
            j = jn; w = wn;                                                  \
            c0 = n0; c1 = n1; c2 = n2;                                       \
        }                                                                    \
    }

// 4B-payload edge loop: weight == 1, pure adds.
#define AGG_LOOP4(EDGEAT)                                                    \
    {                                                                        \
        int e = EDGEAT(j);                                                   \
        uint4 c0, c1; uint2 c2; ROWLD(c0, c1, c2, e)                         \
        while (true) {                                                       \
            int jn = j + 4;                                                  \
            bool more = jn < s1;                                             \
            int jp = more ? jn : j;                                          \
            int en = EDGEAT(jp);                                             \
            uint4 n0, n1; uint2 n2; ROWLD(n0, n1, n2, en)                    \
            float4 v0 = h4f2(make_uint2(c0.x, c0.y));                        \
            float4 v1 = h4f2(make_uint2(c0.z, c0.w));                        \
            float4 v2 = h4f2(make_uint2(c1.x, c1.y));                        \
            float4 v3 = h4f2(make_uint2(c1.z, c1.w));                        \
            float4 v4 = h4f2(c2);                                            \
            ADD4(a0, v0) ADD4(a1, v1) ADD4(a2, v2)                           \
            ADD4(a3, v3) ADD4(a4, v4)                                        \
            if (!more) break;                                                \
            j = jn;                                                          \
            c0 = n0; c1 = n1; c2 = n2;                                       \
        }                                                                    \
    }

#define EDGE_LDS(jj)  sse[(jj) - sb0]
#define EDGE_GBL(jj)  se[(jj)]
#define EDGE_LDS4(jj) sse4[(jj) - sb0]
#define EDGE_GBL4(jj) se4[(jj)]

// MODE 0: layers 1/2 — write o row + BN stats.
// MODE 1: layer 3 — fuse final linear: out[i,0..9] from o1,o2 rows + in-reg o3.
// One node per 4-lane group; block's 64 nodes = contiguous se span staged in LDS.
template<int MODE>
__global__ __launch_bounds__(256)
void agg_kernel(const __half* __restrict__ hsb, const float* __restrict__ dinv,
                const int* __restrict__ row_start, const int2* __restrict__ se,
                const int* __restrict__ eflag,
                const float* __restrict__ bias, float* __restrict__ out,
                float* __restrict__ stat_sum, float* __restrict__ stat_sq,
                const float* __restrict__ o1, const float* __restrict__ o2,
                const float* __restrict__ Wlp, const float* __restrict__ blp,
                int n) {
    __shared__ int2 sse[CAPE];
    int* sse4 = (int*)sse;                  // 2*CAPE ints in same LDS
    const int* se4 = (const int*)se;
    __shared__ float ls[HD], lq[HD];
    __shared__ float sW[600];
    __shared__ float sb[10];
    bool f4 = eflag[0] != 0;
    int base = blockIdx.x * 64;              // 256 threads / 4 lanes = 64 nodes
    int nEnd = base + 64; if (nEnd > n) nEnd = n;
    int sb0 = row_start[base];
    int sb1 = row_start[nEnd];
    int span = sb1 - sb0;
    bool ok = span <= (f4 ? 2 * CAPE : CAPE);
    if (MODE == 0) {
        if (threadIdx.x < HD) { ls[threadIdx.x] = 0.0f; lq[threadIdx.x] = 0.0f; }
    } else {
        for (int i = threadIdx.x; i < 600; i += 256) sW[i] = Wlp[i];
        if (threadIdx.x < 10) sb[threadIdx.x] = blp[threadIdx.x];
    }
    if (ok) {
        if (f4) {
            for (int k = threadIdx.x; k < span; k += 256)
                sse4[k] = __builtin_nontemporal_load(se4 + sb0 + k);
        } else {
            for (int k = threadIdx.x; k < span; k += 256) {
                long long v = __builtin_nontemporal_load(
                    (const long long*)(se + sb0 + k));
                sse[k] = *(const int2*)&v;
            }
        }
    }
    __syncthreads();
    int i = base + (threadIdx.x >> 2), lane = threadIdx.x & 3;
    if (i < n) {
        float di = dinv[i];
        int s0 = row_start[i], s1 = row_start[i + 1];
        float4 a0, a1, a2, a3, a4;
        if (lane == 0) {
            uint4 y0, y1; uint2 y2;
            ROWLD(y0, y1, y2, i)
            a0 = h4f2(make_uint2(y0.x, y0.y));
            a1 = h4f2(make_uint2(y0.z, y0.w));
            a2 = h4f2(make_uint2(y1.x, y1.y));
            a3 = h4f2(make_uint2(y1.z, y1.w));
            a4 = h4f2(y2);
        } else {
            a0 = a1 = a2 = a3 = a4 = make_float4(0.f, 0.f, 0.f, 0.f);
        }
        int j = s0 + lane;
        if (j < s1) {
            if (f4) {
                if (ok) { AGG_LOOP4(EDGE_LDS4) }
                else    { AGG_LOOP4(EDGE_GBL4) }
            } else {
                if (ok) { AGG_LOOP(EDGE_LDS) }
                else    { AGG_LOOP(EDGE_GBL) }
            }
        }
        #define REDX(A, M) \
            A.x += __shfl_xor(A.x, M); A.y += __shfl_xor(A.y, M); \
            A.z += __shfl_xor(A.z, M); A.w += __shfl_xor(A.w, M);
        #define RED4L(A) REDX(A, 1) REDX(A, 2)
        RED4L(a0) RED4L(a1) RED4L(a2) RED4L(a3) RED4L(a4)
        // all 4 lanes now hold the full sums
        float4 acc[5] = {a0, a1, a2, a3, a4};
        float va[HD];
        #pragma unroll
        for (int q = 0; q < 5; ++q) {
            float4 bb = *(const float4*)(bias + 4 * q);
            va[4 * q + 0] = fmaxf(fmaf(acc[q].x, di, bb.x), 0.0f);
            va[4 * q + 1] = fmaxf(fmaf(acc[q].y, di, bb.y), 0.0f);
            va[4 * q + 2] = fmaxf(fmaf(acc[q].z, di, bb.z), 0.0f);
            va[4 * q + 3] = fmaxf(fmaf(acc[q].w, di, bb.w), 0.0f);
        }
        if (MODE == 0) {
            if (lane == 0) {
                #pragma unroll
                for (int q = 0; q < 5; ++q) {
                    ((float4*)out)[i * 5 + q] = make_float4(
                        va[4 * q], va[4 * q + 1], va[4 * q + 2], va[4 * q + 3]);
                    int f = 4 * q;
                    atomicAdd(&ls[f + 0], va[f + 0]); atomicAdd(&lq[f + 0], va[f + 0] * va[f + 0]);
                    atomicAdd(&ls[f + 1], va[f + 1]); atomicAdd(&lq[f + 1], va[f + 1] * va[f + 1]);
                    atomicAdd(&ls[f + 2], va[f + 2]); atomicAdd(&lq[f + 2], va[f + 2] * va[f + 2]);
                    atomicAdd(&ls[f + 3], va[f + 3]); atomicAdd(&lq[f + 3], va[f + 3] * va[f + 3]);
                }
            }
        } else {
            // fused final: load o1,o2 rows (same addrs across quad -> L1 broadcast)
            float r1[HD], r2[HD];
            #pragma unroll
            for (int q = 0; q < 5; ++q) {
                *(float4*)&r1[4 * q] = ((const float4*)(o1 + (size_t)i * HD))[q];
                *(float4*)&r2[4 * q] = ((const float4*)(o2 + (size_t)i * HD))[q];
            }
            for (int c = lane; c < 10; c += 4) {
                float s = sb[c];
                #pragma unroll
                for (int k = 0; k < HD; ++k) s = fmaf(r1[k], sW[k * 10 + c], s);
                #pragma unroll
                for (int k = 0; k < HD; ++k) s = fmaf(r2[k], sW[(HD + k) * 10 + c], s);
                #pragma unroll
                for (int k = 0; k < HD; ++k) s = fmaf(va[k], sW[(2 * HD + k) * 10 + c], s);
                out[(size_t)i * 10 + c] = s;
            }
        }
    }
    if (MODE == 0) {
        __syncthreads();
        if (threadIdx.x < HD) {
            atomicAdd(&stat_sum[threadIdx.x], ls[threadIdx.x]);
            atomicAdd(&stat_sq[threadIdx.x], lq[threadIdx.x]);
        }
    }
}

// BN finalize + fold into next conv: scsh_out = (scale,shift);
// Wp[k][f] = sc[k]*W[k][f]; cvec[f] = sum_k sh[k]*W[k][f]
__global__ __launch_bounds__(512)
void bn_adjust_kernel(const float* __restrict__ sum, const float* __restrict__ sq,
                      const float* __restrict__ g, const float* __restrict__ be,
                      const float* __restrict__ W, float* __restrict__ scsh_out,
                      float* __restrict__ Wp, float* __restrict__ cvec, int n) {
    __shared__ float ssc[HD], ssh[HD];
    int t = threadIdx.x;
    if (t < HD) {
        float inv_n = 1.0f / (float)n;
        float m = sum[t] * inv_n;
        float var = sq[t] * inv_n - m * m;
        float sc = g[t] * rsqrtf(var + EPS);
        float sh = be[t] - m * sc;
        ssc[t] = sc; ssh[t] = sh;
        scsh_out[t] = sc; scsh_out[HD + t] = sh;
    }
    __syncthreads();
    if (t < HD * HD) Wp[t] = ssc[t / HD] * W[t];
    if (t < HD) {
        float acc = 0.0f;
        #pragma unroll
        for (int k = 0; k < HD; ++k) acc = fmaf(ssh[k], W[k * HD + t], acc);
        cvec[t] = acc;
    }
}

// second BN: same as above + build Wlp/blp for the fused final.
// Wlp rows: 0..19 *= sc1, 20..39 *= sc2, 40..59 UNSCALED (o3 block).
__global__ __launch_bounds__(640)
void bn_adjust2_kernel(const float* __restrict__ sum, const float* __restrict__ sq,
                       const float* __restrict__ g, const float* __restrict__ be,
                       const float* __restrict__ W, float* __restrict__ scsh_out,
                       float* __restrict__ Wp, float* __restrict__ cvec,
                       const float* __restrict__ Wl, const float* __restrict__ bl,
                       const float* __restrict__ scsh1,
                       float* __restrict__ Wlp, float* __restrict__ blp, int n) {
    __shared__ float ssc[HD], ssh[HD];
    int t = threadIdx.x;
    if (t < HD) {
        float inv_n = 1.0f / (float)n;
        float m = sum[t] * inv_n;
        float var = sq[t] * inv_n - m * m;
        float sc = g[t] * rsqrtf(var + EPS);
        float sh = be[t] - m * sc;
        ssc[t] = sc; ssh[t] = sh;
        scsh_out[t] = sc; scsh_out[HD + t] = sh;
    }
    __syncthreads();
    if (t < HD * HD) Wp[t] = ssc[t / HD] * W[t];
    if (t < HD) {
        float acc = 0.0f;
        #pragma unroll
        for (int k = 0; k < HD; ++k) acc = fmaf(ssh[k], W[k * HD + t], acc);
        cvec[t] = acc;
    }
    if (t < 600) {
        int k = t / 10;
        float s = (k < HD) ? scsh1[k] : (k < 2 * HD) ? ssc[k - HD] : 1.0f;
        Wlp[t] = s * Wl[t];
    }
    if (t < 10) {
        float acc = bl[t];
        #pragma unroll
        for (int k = 0; k < HD; ++k) acc = fmaf(scsh1[HD + k], Wl[k * 10 + t], acc);
        #pragma unroll
        for (int k = 0; k < HD; ++k) acc = fmaf(ssh[k], Wl[(HD + k) * 10 + t], acc);
        blp[t] = acc;
    }
}

extern "C" void kernel_launch(void* const* d_in, const int* in_sizes, int n_in,
                              void* d_out, int out_size, void* d_ws, size_t ws_size,
                              hipStream_t stream) {
    const float* x   = (const float*)d_in[0];
    const int*   ei  = (const int*)d_in[1];
    const float* ew  = (const float*)d_in[2];
    const float* W1  = (const float*)d_in[3];
    const float* b1  = (const float*)d_in[4];
    const float* g1  = (const float*)d_in[5];
    const float* be1 = (const float*)d_in[6];
    const float* W2  = (const float*)d_in[7];
    const float* b2  = (const float*)d_in[8];
    const float* g2  = (const float*)d_in[9];
    const float* be2 = (const float*)d_in[10];
    const float* W3  = (const float*)d_in[11];
    const float* b3  = (const float*)d_in[12];
    const float* Wl  = (const float*)d_in[13];
    const float* bl  = (const float*)d_in[14];
    float* out = (float*)d_out;

    const int F = in_sizes[3] / HD;       // 128
    const int N = in_sizes[0] / F;        // 100000
    const int E = in_sizes[2];            // 3200000
    const int* src = ei;
    const int* dst = ei + E;
    const int nbv = (N + 127) >> BSH;     // 782 buckets

    char* p = (char*)d_ws;
    auto alloc = [&](size_t bytes) -> void* {
        void* r = (void*)p;
        p += (bytes + 255) & ~(size_t)255;
        return r;
    };
    size_t nh4 = (size_t)N * HD * 4;                         // 8e6 B
    int2*  se      = (int2*) alloc((size_t)E * 8);           // CSR payload
    char*  regionA = (char*) alloc((size_t)E * 8);           // tmp -> hs|_|o1r
    float* o2r     = (float*)alloc(nh4);
    float* dinv    = (float*)alloc((size_t)N * 4);
    int*   row_start = (int*)alloc((size_t)(N + 1) * 4);
    int*   bcnt    = (int*)  alloc(NBMAX * 4);
    int*   bstart  = (int*)  alloc((NBMAX + 1) * 4);
    int*   bcur    = (int*)  alloc(NBMAX * 4);
    float* stats   = (float*)alloc(80 * 4);   // sum1,sq1,sum2,sq2
    float* scsh    = (float*)alloc(80 * 4);   // sc1,sh1,sc2,sh2
    float* zero20  = (float*)alloc(20 * 4);
    float* W2p     = (float*)alloc(400 * 4);
    float* c2      = (float*)alloc(20 * 4);
    float* W3p     = (float*)alloc(400 * 4);
    float* c3      = (float*)alloc(20 * 4);
    float* Wlp     = (float*)alloc(600 * 4);
    float* blp     = (float*)alloc(12 * 4);
    int*   eflag   = (int*)  alloc(4);

    int2*   tmp = (int2*)regionA;
    __half* hs  = (__half*)regionA;                 // 4 MB fp16, fits per-XCD L2
    float*  o1r = (float*)(regionA + 2 * nh4);

    const int B = 256;
    const int GB = 512;                          // blocks for hist/scatter
    const int chunk = (E + GB - 1) / GB;         // 6250 (<= CHUNKMAX)
    int gAgg = (4 * N + B - 1) / B;              // 1563 (4 lanes/node, 64 nodes/block)

    // ---- graph build (shared by all 3 layers) ----
    hipLaunchKernelGGL(init_kernel, dim3(1), dim3(1024), 0, stream,
                       bcnt, stats, zero20, eflag, nbv);
    hipLaunchKernelGGL(bucket_hist_kernel, dim3(GB), dim3(B), 0, stream,
                       dst, ew, bcnt, eflag, E, chunk, nbv);
    hipLaunchKernelGGL(bucket_scan_kernel, dim3(1), dim3(1024), 0, stream,
                       bcnt, bstart, bcur, row_start, N, E, nbv);
    hipLaunchKernelGGL(scatter_kernel, dim3(GB), dim3(B), 0, stream,
                       src, dst, ew, eflag, bcur, tmp, E, chunk, nbv);
    hipLaunchKernelGGL(finalize_kernel, dim3(nbv), dim3(B), 0, stream,
                       tmp, bstart, eflag, se, row_start, dinv, N);

    // ---- layer 1 (no upstream BN: cvec = 0, bias = b1) ----
    hipLaunchKernelGGL((gemm_kernel<128, 16>), dim3((N + 15) / 16), dim3(B), 0, stream,
                       x, W1, zero20, dinv, hs, N);
    hipLaunchKernelGGL((agg_kernel<0>), dim3(gAgg), dim3(B), 0, stream,
                       hs, dinv, row_start, se, eflag, b1, o1r,
                       stats, stats + 20, nullptr, nullptr, nullptr, nullptr, N);
    hipLaunchKernelGGL(bn_adjust_kernel, dim3(1), dim3(512), 0, stream,
                       stats, stats + 20, g1, be1, W2, scsh, W2p, c2, N);

    // ---- layer 2 (BN1 scale in W2p, shift in c2 pre-agg; bias = raw b2) ----
    hipLaunchKernelGGL((gemm_kernel<HD, 64>), dim3((N + 63) / 64), dim3(B), 0, stream,
                       o1r, W2p, c2, dinv, hs, N);
    hipLaunchKernelGGL((agg_kernel<0>), dim3(gAgg), dim3(B), 0, stream,
                       hs, dinv, row_start, se, eflag, b2, o2r,
                       stats + 40, stats + 60, nullptr, nullptr, nullptr, nullptr, N);
    hipLaunchKernelGGL(bn_adjust2_kernel, dim3(1), dim3(640), 0, stream,
                       stats + 40, stats + 60, g2, be2, W3, scsh + 40, W3p, c3,
                       Wl, bl, scsh, Wlp, blp, N);

    // ---- layer 3 + fused final linear (writes d_out directly) ----
    hipLaunchKernelGGL((gemm_kernel<HD, 64>), dim3((N + 63) / 64), dim3(B), 0, stream,
                       o2r, W3p, c3, dinv, hs, N);
    hipLaunchKernelGGL((agg_kernel<1>), dim3(gAgg), dim3(B), 0, stream,
                       hs, dinv, row_start, se, eflag, b3, out,
                       nullptr, nullptr, o1r, o2r, Wlp, blp, N);
}